// Round 22
// baseline (31.177 us; speedup 1.0000x reference)
//
#include <hip/hip_runtime.h>

#define N 512
#define D 128
// vals = cos_sim * ||x_i|| (row-common positive factors dropped: ranks are
// scale-invariant). Range +-~11.4; buckets over [-16,16), monotone => step
// function computed EXACTLY (higher bucket > ; own bucket by float compare).
#define W2_INV 8.0f
#define B_OFF2 16.0f
#define PADV -100.0f     // self-slot: bucket 0, below all real vals
#define NB 256
#define TROWS 128        // tile rows per pass
#define TSTRIDE 132      // float stride (pad 4)

static __device__ __forceinline__ float rcp_fast(float x) {
    return __builtin_amdgcn_rcpf(x);
}

// Single fused kernel: 256 blocks x 512 threads; block b owns rows i0=2b,
// i1=2b+1. Phase A: LDS-tiled GEMV (4 passes x 128 rows). Phase B: per row,
// counting-sort + exact step ranks — ONE element / ONE position per thread
// (512 threads == N elements; R20/R21's double-count OOB bug fixed).
// Finalize: memset-reset ticket, true last-arrival block reduces av[] -> out.
__global__ __launch_bounds__(512) void map_all_kernel(
    const float* __restrict__ x, const int* __restrict__ tgt,
    float2* __restrict__ av, int* __restrict__ ticket,
    float* __restrict__ out)
{
    const int b = blockIdx.x, t = threadIdx.x;
    const int lane = t & 63;
    const int i0 = 2 * b, i1 = 2 * b + 1;

    __shared__ __align__(16) float TD[TROWS * TSTRIDE];  // 66 KiB tile
    __shared__ __align__(16) float xiA[D], xiB[D];
    __shared__ float sd0[N], sd1[N], sss[N];
    __shared__ int hist[NB];
    __shared__ int offs[NB];
    __shared__ int wtot[4];
    __shared__ unsigned gbits[16];
    __shared__ float skey[N];
    __shared__ float red[16];
    __shared__ int amLast;

    // ---- stage xi rows ----
    if (t < 32) ((float4*)xiA)[t] = ((const float4*)(x + i0 * D))[t];
    else if (t < 64) ((float4*)xiB)[t - 32] = ((const float4*)(x + i1 * D))[t - 32];
    __syncthreads();

    // register-cache xi fragments. Granule rotation g = m*8 + ((j+2m)&7):
    // compile-time reg indices; quad lanes hit distinct LDS banks.
    const int r = t >> 2;    // tile-row owned in dot phase [0,128)
    const int m = t & 3;     // quad slot
    float4 ra[8], rb[8];
#pragma unroll
    for (int j = 0; j < 8; ++j) {
        int g = m * 8 + ((j + 2 * m) & 7);
        ra[j] = ((const float4*)xiA)[g];
        rb[j] = ((const float4*)xiB)[g];
    }

    // ---- phase A: 4 passes of 128 rows ----
#pragma unroll 1
    for (int p = 0; p < 4; ++p) {
        __syncthreads();   // previous pass's TD fully consumed
#pragma unroll
        for (int s = 0; s < 8; ++s) {
            int ch = t + 512 * s;            // [0,4096)
            int row = ch >> 5, c4 = ch & 31;
            *(float4*)(TD + row * TSTRIDE + c4 * 4) =
                *(const float4*)(x + (p * TROWS + row) * D + c4 * 4);
        }
        __syncthreads();

        float d0 = 0.f, d1 = 0.f, ss = 0.f;
#pragma unroll
        for (int j = 0; j < 8; ++j) {
            int g = m * 8 + ((j + 2 * m) & 7);
            float4 v = *(const float4*)(TD + r * TSTRIDE + g * 4);
            d0 = fmaf(v.x, ra[j].x, d0); d0 = fmaf(v.y, ra[j].y, d0);
            d0 = fmaf(v.z, ra[j].z, d0); d0 = fmaf(v.w, ra[j].w, d0);
            d1 = fmaf(v.x, rb[j].x, d1); d1 = fmaf(v.y, rb[j].y, d1);
            d1 = fmaf(v.z, rb[j].z, d1); d1 = fmaf(v.w, rb[j].w, d1);
            ss = fmaf(v.x, v.x, ss); ss = fmaf(v.y, v.y, ss);
            ss = fmaf(v.z, v.z, ss); ss = fmaf(v.w, v.w, ss);
        }
#pragma unroll
        for (int off = 1; off < 4; off <<= 1) {   // quad reduce (same wave)
            d0 += __shfl_xor(d0, off);
            d1 += __shfl_xor(d1, off);
            ss += __shfl_xor(ss, off);
        }
        if (m == 0) {
            int grow = p * TROWS + r;
            sd0[grow] = d0; sd1[grow] = d1; sss[grow] = ss;
        }
    }
    __syncthreads();

    // ---- per-element setup: thread t owns element t (exactly one) ----
    const int ti0 = tgt[i0], ti1 = tgt[i1];
    const int tgE = tgt[t];
    const float invT = rcp_fast(fmaxf(sqrtf(sss[t]), 1e-8f));
    const float dotA = sd0[t], dotB = sd1[t];

    float apOut[2] = {0.f, 0.f}, npOut[2] = {0.f, 0.f};

    // ---- phase B: sort + exact step ranks, per row ----
#pragma unroll 1
    for (int ri = 0; ri < 2; ++ri) {
        const int irow = ri ? i1 : i0;
        const int tirow = ri ? ti1 : ti0;
        const float val = (t == irow) ? PADV : (ri ? dotB : dotA) * invT;
        const int gti = (t != irow && tgE == tirow) ? 1 : 0;
        int q = (int)((val + B_OFF2) * W2_INV);
        q = max(0, min(NB - 1, q));

        __syncthreads();   // previous row's LDS fully consumed
        if (t < NB) { hist[t] = 0; offs[t] = 0; }
        if (t < 16) gbits[t] = 0u;
        __syncthreads();
        atomicAdd(&hist[q], (1 << 10) | gti);   // one add per thread: N total
        __syncthreads();

        // wave-level inclusive scan (waves 0-3; packed fields)
        int v = (t < NB) ? hist[t] : 0;
#pragma unroll
        for (int off = 1; off < 64; off <<= 1) {
            int u = __shfl_up(v, off);
            if (lane >= off) v += u;
        }
        if (t < NB && lane == 63) wtot[t >> 6] = v;
        __syncthreads();
        if (t < NB) {
            int w = t >> 6, add = 0;
            if (w > 0) add += wtot[0];
            if (w > 1) add += wtot[1];
            if (w > 2) add += wtot[2];
            hist[t] = v + add;
        }
        __syncthreads();

        // scatter: one element per thread -> pos in [0, N)
        {
            int base = (q > 0) ? (hist[q - 1] >> 10) : 0;
            int pos = base + atomicAdd(&offs[q], 1);
            skey[pos] = val;
            if (gti) atomicOr(&gbits[pos >> 5], 1u << (pos & 31));
        }
        __syncthreads();

        const int totGt = hist[NB - 1] & 1023;

        // rank for sorted position p = t (exactly one per thread)
        const float rj = skey[t];
        const int gtj = (gbits[t >> 5] >> (t & 31)) & 1;
        int qp = (int)((rj + B_OFF2) * W2_INV);
        qp = max(0, min(NB - 1, qp));
        const int packCur = hist[qp];
        const int bstart = (qp > 0) ? (hist[qp - 1] >> 10) : 0;
        const int bend = packCur >> 10;

        int cnt = N - bend;                 // strictly higher buckets: all >
        int gcnt = totGt - (packCur & 1023);
        for (int idx = bstart; idx < bend; ++idx) {  // own bucket: exact
            bool above = skey[idx] > rj;
            int g = (gbits[idx >> 5] >> (idx & 31)) & 1;
            cnt += above ? 1 : 0;
            gcnt += (above && g) ? 1 : 0;
        }
        float dsum = (float)cnt + 1.0f;     // +0.5 self-tie +0.5 formula
        float gsum = (float)gcnt + 0.5f * (float)gtj;
        float apAcc = gtj ? (gsum * rcp_fast(dsum)) : 0.f;
        float npAcc = (float)gtj;

        // block reduction (8 waves)
#pragma unroll
        for (int off = 32; off; off >>= 1) {
            apAcc += __shfl_down(apAcc, off);
            npAcc += __shfl_down(npAcc, off);
        }
        if (lane == 0) { red[(t >> 6) * 2] = apAcc; red[(t >> 6) * 2 + 1] = npAcc; }
        __syncthreads();
        if (t == 0) {
            float A = 0.f, P = 0.f;
#pragma unroll
            for (int kk = 0; kk < 8; ++kk) { A += red[2 * kk]; P += red[2 * kk + 1]; }
            apOut[ri] = (P > 0.f) ? (A * rcp_fast(P)) : 0.f;
            npOut[ri] = (P > 0.f) ? 1.f : 0.f;
        }
    }

    if (t == 0) {
        av[i0] = make_float2(apOut[0], npOut[0]);
        av[i1] = make_float2(apOut[1], npOut[1]);
        __threadfence();                       // release av
        int old = atomicAdd(ticket, 1);
        amLast = (old == (int)gridDim.x - 1) ? 1 : 0;  // ticket memset to 0
    }
    __syncthreads();

    if (amLast) {   // true last arrival: all av[] written & visible
        __threadfence();                       // acquire
        float2 p = av[t];
        float a = p.x, vv = p.y;
#pragma unroll
        for (int off = 32; off; off >>= 1) {
            a += __shfl_down(a, off);
            vv += __shfl_down(vv, off);
        }
        __syncthreads();
        if (lane == 0) { red[(t >> 6) * 2] = a; red[(t >> 6) * 2 + 1] = vv; }
        __syncthreads();
        if (t == 0) {
            float A = 0.f, V = 0.f;
#pragma unroll
            for (int kk = 0; kk < 8; ++kk) { A += red[2 * kk]; V += red[2 * kk + 1]; }
            out[0] = 1.0f - A * rcp_fast(V);
        }
    }
}

extern "C" void kernel_launch(void* const* d_in, const int* in_sizes, int n_in,
                              void* d_out, int out_size, void* d_ws, size_t ws_size,
                              hipStream_t stream) {
    const float* x = (const float*)d_in[0];
    const int* tgt = (const int*)d_in[1];
    float* out = (float*)d_out;

    float2* av = (float2*)d_ws;                      // 4 KB
    int* ticket = (int*)((char*)d_ws + 4096);        // 4 B

    // deterministic ticket reset (async, graph-capture-safe)
    hipMemsetAsync(ticket, 0, sizeof(int), stream);
    map_all_kernel<<<N / 2, 512, 0, stream>>>(x, tgt, av, ticket, out);
}

// Round 23
// 30.530 us; speedup vs baseline: 1.0212x; 1.0212x over previous
//
#include <hip/hip_runtime.h>

#define N 512
#define D 128
// rs = cos_sim * 1442.7 (scale irrelevant to ranks; kept for bucket ranges)
#define RS_SCALE 1442.6950408889634f
// 256 buckets over [-1460,1460); bucketing monotone => step function EXACT
// (higher bucket => strictly greater; own bucket by float compare).
#define W_INV 0.08767123287671233f   // 256 / 2920
#define B_OFF 1460.0f
#define PADV -1600.0f                // self-slot: bucket 0, below all real rs
#define NB 256

static __device__ __forceinline__ float rcp_fast(float x) {
    return __builtin_amdgcn_rcpf(x);
}

// ---------------- K1: norm-fused scaled-sim GEMM ----------------------------
// 256 blocks (32 row-panels x 8): each block stages ONE 16-row A panel
// (+norms via shfl reduce) and processes TWO 32-col B panels -> half the
// block cold-starts of R19's K1, A-staging reused. Math identical.
__global__ __launch_bounds__(256) void map_sim_kernel(
    const float* __restrict__ x, float* __restrict__ rs,
    int* __restrict__ ticket)
{
    const int bi = blockIdx.x;    // 32 row-panels of 16 (A)
    const int bjj = blockIdx.y;   // 8 -> B panels 2*bjj, 2*bjj+1
    const int t = threadIdx.x;
    __shared__ float As[16 * D];
    __shared__ float Bs[32 * D];
    __shared__ float ssArr[48];
    __shared__ float invArr[48];

    if (bi == 0 && bjj == 0 && t == 0) *ticket = 0;  // reset fence counter

    const int sl = t & 31;
    // stage A once (16 rows; 32 consecutive lanes = one full row)
#pragma unroll
    for (int s = 0; s < 2; ++s) {
        int ch = t + 256 * s;
        int row = ch >> 5, c4 = ch & 31;
        float4 v = *(const float4*)(x + (bi * 16 + row) * D + c4 * 4);
        *(float4*)(As + row * D + ((c4 ^ row) << 2)) = v;
        float ss = v.x * v.x + v.y * v.y + v.z * v.z + v.w * v.w;
#pragma unroll
        for (int off = 16; off; off >>= 1) ss += __shfl_xor(ss, off);
        if (sl == 0) ssArr[row] = ss;
    }
    __syncthreads();
    if (t < 16) invArr[t] = rcp_fast(fmaxf(sqrtf(ssArr[t]), 1e-8f));
    __syncthreads();

    const int c = t & 31;
    const int rp = t >> 5;
    const int ra0 = 2 * rp, ra1 = 2 * rp + 1;
    const float sA0 = invArr[ra0] * RS_SCALE;
    const float sA1 = invArr[ra1] * RS_SCALE;

#pragma unroll 1
    for (int half = 0; half < 2; ++half) {
        const int bj = 2 * bjj + half;
        __syncthreads();   // previous half's Bs fully consumed
        // stage B panel (32 rows) + norms
#pragma unroll
        for (int s = 0; s < 4; ++s) {
            int ch = t + 256 * s;
            int row = ch >> 5, c4 = ch & 31;
            float4 v = *(const float4*)(x + (bj * 32 + row) * D + c4 * 4);
            *(float4*)(Bs + row * D + ((c4 ^ row) << 2)) = v;
            float ss = v.x * v.x + v.y * v.y + v.z * v.z + v.w * v.w;
#pragma unroll
            for (int off = 16; off; off >>= 1) ss += __shfl_xor(ss, off);
            if (sl == 0) ssArr[16 + row] = ss;
        }
        __syncthreads();
        if (t < 32) invArr[16 + t] = rcp_fast(fmaxf(sqrtf(ssArr[16 + t]), 1e-8f));
        __syncthreads();

        float acc0 = 0.f, acc1 = 0.f;
#pragma unroll 8
        for (int k4 = 0; k4 < D / 4; ++k4) {
            float4 b = *(const float4*)(Bs + c * D + ((k4 ^ c) << 2));
            float4 a0 = *(const float4*)(As + ra0 * D + ((k4 ^ ra0) << 2));
            float4 a1 = *(const float4*)(As + ra1 * D + ((k4 ^ ra1) << 2));
            acc0 = fmaf(a0.x, b.x, acc0); acc0 = fmaf(a0.y, b.y, acc0);
            acc0 = fmaf(a0.z, b.z, acc0); acc0 = fmaf(a0.w, b.w, acc0);
            acc1 = fmaf(a1.x, b.x, acc1); acc1 = fmaf(a1.y, b.y, acc1);
            acc1 = fmaf(a1.z, b.z, acc1); acc1 = fmaf(a1.w, b.w, acc1);
        }
        const float sBc = invArr[16 + c];
        const int gc = bj * 32 + c;
        rs[(bi * 16 + ra0) * N + gc] = acc0 * sA0 * sBc;
        rs[(bi * 16 + ra1) * N + gc] = acc1 * sA1 * sBc;
    }
}

// ---------------- K2: counting-sort + EXACT STEP ranks (R19, unchanged) -----
// 256 threads, 2 elements/positions per thread. dsum = count(> ) + 1.0;
// gsum = gt_above + 0.5*gtj. No transcendentals.
__global__ __launch_bounds__(256) void map_ap_kernel(
    const float* __restrict__ rs, const int* __restrict__ tgt,
    float2* __restrict__ av, int* __restrict__ ticket,
    float* __restrict__ out)
{
    const int i = blockIdx.x, t = threadIdx.x;
    const int lane = t & 63;
    __shared__ int hist[NB];    // packed (count<<10)|gtcount -> inclusive scan
    __shared__ int offs[NB];
    __shared__ int wtot[4];
    __shared__ unsigned gbits[16];   // gt bitmask by sorted position
    __shared__ float skey[N];        // bucket-sorted keys
    __shared__ float red[8];
    __shared__ int amLast;

    const int ti = tgt[i];
    const float v0raw = rs[i * N + t];
    const float v1raw = rs[i * N + t + 256];
    const int tg0 = tgt[t], tg1 = tgt[t + 256];

    hist[t] = 0;
    offs[t] = 0;
    if (t < 16) gbits[t] = 0u;

    float val[2]; int gti[2], q[2];
    val[0] = (t == i) ? PADV : v0raw;
    val[1] = (t + 256 == i) ? PADV : v1raw;
    gti[0] = (t != i && tg0 == ti) ? 1 : 0;
    gti[1] = (t + 256 != i && tg1 == ti) ? 1 : 0;
#pragma unroll
    for (int e = 0; e < 2; ++e) {
        int qq = (int)((val[e] + B_OFF) * W_INV);
        q[e] = max(0, min(NB - 1, qq));
    }
    __syncthreads();
    atomicAdd(&hist[q[0]], (1 << 10) | gti[0]);
    atomicAdd(&hist[q[1]], (1 << 10) | gti[1]);
    __syncthreads();

    int v = hist[t];
#pragma unroll
    for (int off = 1; off < 64; off <<= 1) {
        int u = __shfl_up(v, off);
        if (lane >= off) v += u;
    }
    if (lane == 63) wtot[t >> 6] = v;
    __syncthreads();
    {
        int w = t >> 6, add = 0;
        if (w > 0) add += wtot[0];
        if (w > 1) add += wtot[1];
        if (w > 2) add += wtot[2];
        hist[t] = v + add;
    }
    __syncthreads();

#pragma unroll
    for (int e = 0; e < 2; ++e) {
        int base = (q[e] > 0) ? (hist[q[e] - 1] >> 10) : 0;
        int pos = base + atomicAdd(&offs[q[e]], 1);
        skey[pos] = val[e];
        if (gti[e]) atomicOr(&gbits[pos >> 5], 1u << (pos & 31));
    }
    __syncthreads();

    const int totGt = hist[NB - 1] & 1023;

    float apAcc = 0.f, npAcc = 0.f;
#pragma unroll
    for (int ri = 0; ri < 2; ++ri) {
        const int p = t + 256 * ri;
        const float rj = skey[p];
        const int gtj = (gbits[p >> 5] >> (p & 31)) & 1;
        int qp = (int)((rj + B_OFF) * W_INV);
        qp = max(0, min(NB - 1, qp));
        const int packCur = hist[qp];
        const int bstart = (qp > 0) ? (hist[qp - 1] >> 10) : 0;
        const int bend = packCur >> 10;

        int cnt = N - bend;
        int gcnt = totGt - (packCur & 1023);
        for (int idx = bstart; idx < bend; ++idx) {
            bool above = skey[idx] > rj;
            int g = (gbits[idx >> 5] >> (idx & 31)) & 1;
            cnt += above ? 1 : 0;
            gcnt += (above && g) ? 1 : 0;
        }
        float dsum = (float)cnt + 1.0f;     // +0.5 self-tie +0.5 formula
        float gsum = (float)gcnt + 0.5f * (float)gtj;
        apAcc += gtj ? (gsum * rcp_fast(dsum)) : 0.f;
        npAcc += (float)gtj;
    }

#pragma unroll
    for (int off = 32; off; off >>= 1) {
        apAcc += __shfl_down(apAcc, off);
        npAcc += __shfl_down(npAcc, off);
    }
    if (lane == 0) { red[(t >> 6) * 2] = apAcc; red[(t >> 6) * 2 + 1] = npAcc; }
    __syncthreads();
    if (t == 0) {
        float A = red[0] + red[2] + red[4] + red[6];
        float P = red[1] + red[3] + red[5] + red[7];
        av[i] = make_float2((P > 0.f) ? (A * rcp_fast(P)) : 0.f,
                            (P > 0.f) ? 1.f : 0.f);
        __threadfence();                       // release av[i]
        int old = atomicAdd(ticket, 1);
        amLast = (old == (int)gridDim.x - 1) ? 1 : 0;
    }
    __syncthreads();

    if (amLast) {
        __threadfence();                       // acquire
        float2 p0 = av[t], p1 = av[t + 256];
        float a = p0.x + p1.x, vv = p0.y + p1.y;
#pragma unroll
        for (int off = 32; off; off >>= 1) {
            a += __shfl_down(a, off);
            vv += __shfl_down(vv, off);
        }
        if (lane == 0) { red[(t >> 6) * 2] = a; red[(t >> 6) * 2 + 1] = vv; }
        __syncthreads();
        if (t == 0) {
            float A = red[0] + red[2] + red[4] + red[6];
            float V = red[1] + red[3] + red[5] + red[7];
            out[0] = 1.0f - A * rcp_fast(V);
        }
    }
}

extern "C" void kernel_launch(void* const* d_in, const int* in_sizes, int n_in,
                              void* d_out, int out_size, void* d_ws, size_t ws_size,
                              hipStream_t stream) {
    const float* x = (const float*)d_in[0];
    const int* tgt = (const int*)d_in[1];
    float* out = (float*)d_out;

    float* rs = (float*)d_ws;                                 // 1 MB
    float2* av = (float2*)((char*)d_ws + N * N * 4);          // 4 KB
    int* ticket = (int*)((char*)d_ws + N * N * 4 + N * 8);    // 4 B

    map_sim_kernel<<<dim3(32, 8), 256, 0, stream>>>(x, rs, ticket);
    map_ap_kernel<<<N, 256, 0, stream>>>(rs, tgt, av, ticket, out);
}

// Round 24
// 27.118 us; speedup vs baseline: 1.1497x; 1.1258x over previous
//
#include <hip/hip_runtime.h>

#define N 512
#define D 128
// 1000 * log2(e): scaled sims rs = cos_sim * 1442.7 (log2-units of sigmoid arg)
#define RS_SCALE 1442.6950408889634f
// bucket width ~11.4 over [-1460, 1460]; bucketing is MONOTONE so the step
// function is computed EXACTLY (higher bucket => strictly greater value;
// own bucket resolved by exact float compares). No sigmoid window needed.
#define W_INV 0.08767123287671233f   // 256 / 2920
#define B_OFF 1460.0f
#define PADV -1600.0f                // self-slot: clamps to bucket 0, below all
#define NB 256

static __device__ __forceinline__ float rcp_fast(float x) {
    return __builtin_amdgcn_rcpf(x);
}

// ---------------- K1: norm-fused scaled-sim GEMM (16x32 tiles, 512 blocks) --
// Stages full rows per half-wave, shfl square-sum reduce gives row norms
// free; epilogue writes rs = cos_sim * RS_SCALE.
__global__ __launch_bounds__(256) void map_sim_kernel(
    const float* __restrict__ x, float* __restrict__ rs,
    int* __restrict__ ticket)
{
    const int bi = blockIdx.x;   // 32 row-panels of 16 (A)
    const int bj = blockIdx.y;   // 16 col-panels of 32 (B)
    const int t = threadIdx.x;
    __shared__ float As[16 * D];
    __shared__ float Bs[32 * D];
    __shared__ float ssArr[48];
    __shared__ float invArr[48];

    if (bi == 0 && bj == 0 && t == 0) *ticket = 0;  // reset fence counter

    const int sl = t & 31;
#pragma unroll
    for (int s = 0; s < 2; ++s) {
        int ch = t + 256 * s;
        int row = ch >> 5, c4 = ch & 31;
        float4 v = *(const float4*)(x + (bi * 16 + row) * D + c4 * 4);
        *(float4*)(As + row * D + ((c4 ^ row) << 2)) = v;
        float ss = v.x * v.x + v.y * v.y + v.z * v.z + v.w * v.w;
#pragma unroll
        for (int off = 16; off; off >>= 1) ss += __shfl_xor(ss, off);
        if (sl == 0) ssArr[row] = ss;
    }
#pragma unroll
    for (int s = 0; s < 4; ++s) {
        int ch = t + 256 * s;
        int row = ch >> 5, c4 = ch & 31;
        float4 v = *(const float4*)(x + (bj * 32 + row) * D + c4 * 4);
        *(float4*)(Bs + row * D + ((c4 ^ row) << 2)) = v;
        float ss = v.x * v.x + v.y * v.y + v.z * v.z + v.w * v.w;
#pragma unroll
        for (int off = 16; off; off >>= 1) ss += __shfl_xor(ss, off);
        if (sl == 0) ssArr[16 + row] = ss;
    }
    __syncthreads();
    if (t < 48) invArr[t] = rcp_fast(fmaxf(sqrtf(ssArr[t]), 1e-8f));
    __syncthreads();

    const int c = t & 31;
    const int rp = t >> 5;
    const int ra0 = 2 * rp, ra1 = 2 * rp + 1;
    float acc0 = 0.f, acc1 = 0.f;
#pragma unroll 8
    for (int k4 = 0; k4 < D / 4; ++k4) {
        float4 b = *(const float4*)(Bs + c * D + ((k4 ^ c) << 2));
        float4 a0 = *(const float4*)(As + ra0 * D + ((k4 ^ ra0) << 2));
        float4 a1 = *(const float4*)(As + ra1 * D + ((k4 ^ ra1) << 2));
        acc0 = fmaf(a0.x, b.x, acc0); acc0 = fmaf(a0.y, b.y, acc0);
        acc0 = fmaf(a0.z, b.z, acc0); acc0 = fmaf(a0.w, b.w, acc0);
        acc1 = fmaf(a1.x, b.x, acc1); acc1 = fmaf(a1.y, b.y, acc1);
        acc1 = fmaf(a1.z, b.z, acc1); acc1 = fmaf(a1.w, b.w, acc1);
    }
    const float sA0 = invArr[ra0] * RS_SCALE;
    const float sA1 = invArr[ra1] * RS_SCALE;
    const float sBc = invArr[16 + c];
    const int gc = bj * 32 + c;
    rs[(bi * 16 + ra0) * N + gc] = acc0 * sA0 * sBc;
    rs[(bi * 16 + ra1) * N + gc] = acc1 * sA1 * sBc;
}

// ---------------- K2: counting-sort + EXACT STEP ranks (no sigmoids) --------
// 256 threads, 2 elements/positions per thread. dsum = count(val_l > val_j)
// + 1.0; gsum = gt_above + 0.5*gtj. Higher buckets via scanned hist suffix;
// own bucket via exact compares.
__global__ __launch_bounds__(256) void map_ap_kernel(
    const float* __restrict__ rs, const int* __restrict__ tgt,
    float2* __restrict__ av, int* __restrict__ ticket,
    float* __restrict__ out)
{
    const int i = blockIdx.x, t = threadIdx.x;
    const int lane = t & 63;
    __shared__ int hist[NB];    // packed (count<<10)|gtcount -> inclusive scan
    __shared__ int offs[NB];
    __shared__ int wtot[4];
    __shared__ unsigned gbits[16];   // gt bitmask by sorted position
    __shared__ float skey[N];        // bucket-sorted keys
    __shared__ float red[8];
    __shared__ int amLast;

    // prologue: coalesced loads (rs pre-scaled by K1)
    const int ti = tgt[i];
    const float v0raw = rs[i * N + t];
    const float v1raw = rs[i * N + t + 256];
    const int tg0 = tgt[t], tg1 = tgt[t + 256];

    hist[t] = 0;
    offs[t] = 0;
    if (t < 16) gbits[t] = 0u;

    float val[2]; int gti[2], q[2];
    val[0] = (t == i) ? PADV : v0raw;
    val[1] = (t + 256 == i) ? PADV : v1raw;
    gti[0] = (t != i && tg0 == ti) ? 1 : 0;
    gti[1] = (t + 256 != i && tg1 == ti) ? 1 : 0;
#pragma unroll
    for (int e = 0; e < 2; ++e) {
        int qq = (int)((val[e] + B_OFF) * W_INV);
        q[e] = max(0, min(NB - 1, qq));
    }
    __syncthreads();
    atomicAdd(&hist[q[0]], (1 << 10) | gti[0]);
    atomicAdd(&hist[q[1]], (1 << 10) | gti[1]);
    __syncthreads();

    // wave-level inclusive scan of hist[0..255] (packed fields scan together)
    int v = hist[t];
#pragma unroll
    for (int off = 1; off < 64; off <<= 1) {
        int u = __shfl_up(v, off);
        if (lane >= off) v += u;
    }
    if (lane == 63) wtot[t >> 6] = v;
    __syncthreads();
    {
        int w = t >> 6, add = 0;
        if (w > 0) add += wtot[0];
        if (w > 1) add += wtot[1];
        if (w > 2) add += wtot[2];
        hist[t] = v + add;
    }
    __syncthreads();

    // scatter both elements: key + gt bit by sorted position
#pragma unroll
    for (int e = 0; e < 2; ++e) {
        int base = (q[e] > 0) ? (hist[q[e] - 1] >> 10) : 0;
        int pos = base + atomicAdd(&offs[q[e]], 1);
        skey[pos] = val[e];
        if (gti[e]) atomicOr(&gbits[pos >> 5], 1u << (pos & 31));
    }
    __syncthreads();

    const int totGt = hist[NB - 1] & 1023;

    float apAcc = 0.f, npAcc = 0.f;
#pragma unroll
    for (int ri = 0; ri < 2; ++ri) {
        const int p = t + 256 * ri;     // sorted position
        const float rj = skey[p];
        const int gtj = (gbits[p >> 5] >> (p & 31)) & 1;
        int qp = (int)((rj + B_OFF) * W_INV);
        qp = max(0, min(NB - 1, qp));
        const int packCur = hist[qp];
        const int bstart = (qp > 0) ? (hist[qp - 1] >> 10) : 0;
        const int bend = packCur >> 10;

        int cnt = N - bend;                 // strictly higher buckets: all >
        int gcnt = totGt - (packCur & 1023);
        for (int idx = bstart; idx < bend; ++idx) {  // own bucket: exact
            bool above = skey[idx] > rj;
            int g = (gbits[idx >> 5] >> (idx & 31)) & 1;
            cnt += above ? 1 : 0;
            gcnt += (above && g) ? 1 : 0;
        }
        // denom = count_above + 0.5 (self tie) + 0.5 (formula constant)
        float dsum = (float)cnt + 1.0f;
        float gsum = (float)gcnt + 0.5f * (float)gtj;
        apAcc += gtj ? (gsum * rcp_fast(dsum)) : 0.f;  // pad pos: gtj = 0
        npAcc += (float)gtj;
    }

    // block reduction (4 waves)
#pragma unroll
    for (int off = 32; off; off >>= 1) {
        apAcc += __shfl_down(apAcc, off);
        npAcc += __shfl_down(npAcc, off);
    }
    if (lane == 0) { red[(t >> 6) * 2] = apAcc; red[(t >> 6) * 2 + 1] = npAcc; }
    __syncthreads();
    if (t == 0) {
        float A = red[0] + red[2] + red[4] + red[6];
        float P = red[1] + red[3] + red[5] + red[7];
        av[i] = make_float2((P > 0.f) ? (A * rcp_fast(P)) : 0.f,
                            (P > 0.f) ? 1.f : 0.f);
        __threadfence();                       // release av[i]
        int old = atomicAdd(ticket, 1);
        amLast = (old == (int)gridDim.x - 1) ? 1 : 0;
    }
    __syncthreads();

    if (amLast) {  // last block (uniform) reduces av[] and writes out
        __threadfence();                       // acquire
        float2 p0 = av[t], p1 = av[t + 256];
        float a = p0.x + p1.x, vv = p0.y + p1.y;
#pragma unroll
        for (int off = 32; off; off >>= 1) {
            a += __shfl_down(a, off);
            vv += __shfl_down(vv, off);
        }
        if (lane == 0) { red[(t >> 6) * 2] = a; red[(t >> 6) * 2 + 1] = vv; }
        __syncthreads();
        if (t == 0) {
            float A = red[0] + red[2] + red[4] + red[6];
            float V = red[1] + red[3] + red[5] + red[7];
            out[0] = 1.0f - A * rcp_fast(V);
        }
    }
}

extern "C" void kernel_launch(void* const* d_in, const int* in_sizes, int n_in,
                              void* d_out, int out_size, void* d_ws, size_t ws_size,
                              hipStream_t stream) {
    const float* x = (const float*)d_in[0];
    const int* tgt = (const int*)d_in[1];
    float* out = (float*)d_out;

    float* rs = (float*)d_ws;                                 // 1 MB
    float2* av = (float2*)((char*)d_ws + N * N * 4);          // 4 KB
    int* ticket = (int*)((char*)d_ws + N * N * 4 + N * 8);    // 4 B

    map_sim_kernel<<<dim3(32, 16), 256, 0, stream>>>(x, rs, ticket);
    map_ap_kernel<<<N, 256, 0, stream>>>(rs, tgt, av, ticket, out);
}